// Round 5
// baseline (84.540 us; speedup 1.0000x reference)
//
#include <hip/hip_runtime.h>

#define NN 2048
#define NH 4
#define COLS 256   // NH*F_OUT

typedef __attribute__((ext_vector_type(8))) short short8;
typedef __attribute__((ext_vector_type(4))) float f32x4;
typedef __attribute__((ext_vector_type(4))) int i32x4;
typedef __attribute__((ext_vector_type(4))) unsigned u32x4;

__device__ __forceinline__ ushort f2bf(float x) {
  union { float f; unsigned u; } v; v.f = x;
  unsigned r = v.u + 0x7fffu + ((v.u >> 16) & 1u);
  return (ushort)(r >> 16);
}
__device__ __forceinline__ unsigned cvtpk(float lo, float hi) {
  unsigned r;
  asm("v_cvt_pk_bf16_f32 %0, %1, %2" : "=v"(r) : "v"(lo), "v"(hi));
  return r;
}

// ---------------------------------------------------------------------------
// Kernel 1: h = X @ W (f32 accum), emit:
//   hT : bf16 [bh][f][n]; s_src/s_dst : f32 [bh][n], PRE-SCALED by log2(e)
//   so k2 can use v_exp_f32 (2^x) directly: exp(leaky(x)) == 2^(leaky(x*log2e)).
// ---------------------------------------------------------------------------
__global__ __launch_bounds__(256) void k1_prep(
    const float* __restrict__ nf, const float* __restrict__ W,
    const float* __restrict__ att, ushort* __restrict__ hT,
    float* __restrict__ s_src, float* __restrict__ s_dst)
{
  const int tid = threadIdx.x;
  const int head = tid >> 6, lane = tid & 63;   // lane == f for this column
  const int bid = blockIdx.x;

  float w[64];
  #pragma unroll
  for (int f = 0; f < 64; ++f) w[f] = W[f * COLS + tid];   // coalesced

  const float LOG2E = 1.4426950408889634f;
  const float asrc = att[head * 128 + lane] * LOG2E;
  const float adst = att[head * 128 + 64 + lane] * LOG2E;

  __shared__ float xs[512];   // 8 rows x 64 features

  #pragma unroll 1
  for (int g = 0; g < 2; ++g) {
    const int m0 = bid * 16 + g * 8;
    __syncthreads();
    xs[tid]       = nf[m0 * 64 + tid];
    xs[tid + 256] = nf[m0 * 64 + 256 + tid];
    __syncthreads();

    float hv[8];
    #pragma unroll
    for (int rr = 0; rr < 8; ++rr) {
      float acc = 0.f;
      #pragma unroll
      for (int f = 0; f < 64; ++f) acc = fmaf(xs[rr * 64 + f], w[f], acc);
      hv[rr] = acc;
      float vs = acc * asrc, vd = acc * adst;
      #pragma unroll
      for (int off = 32; off > 0; off >>= 1) {
        vs += __shfl_xor(vs, off);
        vd += __shfl_xor(vd, off);
      }
      if (lane == 0) {
        const int m = m0 + rr;
        const int b = m >> 11, n = m & (NN - 1);
        s_src[(b * NH + head) * NN + n] = vs;
        s_dst[(b * NH + head) * NN + n] = vd;
      }
    }

    const int b = m0 >> 11, n0 = m0 & (NN - 1);
    unsigned pk[4];
    #pragma unroll
    for (int e = 0; e < 4; ++e)
      pk[e] = (unsigned)f2bf(hv[2 * e]) | ((unsigned)f2bf(hv[2 * e + 1]) << 16);
    uint4 vv; vv.x = pk[0]; vv.y = pk[1]; vv.z = pk[2]; vv.w = pk[3];
    *(uint4*)(hT + (((size_t)(b * NH + head) * 64 + lane) * NN) + n0) = vv;
  }
}

// ---------------------------------------------------------------------------
// Kernel 2: fused mask + leakyrelu + softmax + P@H via MFMA 16x16x32 bf16.
// grid = B*(N/32) = 256 blocks x 1024 threads (16 waves).
// wave wv: head = wv>>2, js = wv&3 integrates j in [js*512,(js+1)*512).
// Denominator: accd = mfma(P, ones) -> lands in acc row layout, no shuffles.
// Cross-js reduction: 40 KB LDS buffer, 3 staged rounds into js==0 waves.
// ---------------------------------------------------------------------------
__global__ __launch_bounds__(1024) void k2_main(
    const int* __restrict__ adj, const ushort* __restrict__ hT,
    const float* __restrict__ s_src, const float* __restrict__ s_dst,
    float* __restrict__ out)
{
  const int tid = threadIdx.x;
  const int wv  = tid >> 6;
  const int w   = wv >> 2;            // head
  const int js  = wv & 3;             // j-quarter
  const int l   = tid & 63;
  const int bid = blockIdx.x;
  const int b   = bid >> 6;
  const int i0  = (bid & 63) << 5;

  const int bh   = b * NH + w;
  const int r16  = l & 15;
  const int grp  = l >> 4;
  const int koff = grp << 3;

  const float ssl = s_src[bh * NN + i0 + r16];
  const float ssh = s_src[bh * NN + i0 + 16 + r16];

  const float*  sdp  = s_dst + bh * NN;
  const int*    adjl = adj + (size_t)(b * NN + i0 + r16) * NN;
  const int*    adjh = adjl + (size_t)16 * NN;
  const ushort* ht   = hT + ((size_t)bh * 64 + r16) * NN + koff;

  const short8 ones = {(short)0x3F80, (short)0x3F80, (short)0x3F80, (short)0x3F80,
                       (short)0x3F80, (short)0x3F80, (short)0x3F80, (short)0x3F80};

  f32x4 acc[8];   // [s*4+t]
  #pragma unroll
  for (int q = 0; q < 8; ++q) acc[q] = (f32x4){0.f, 0.f, 0.f, 0.f};
  f32x4 acd0 = (f32x4){0.f, 0.f, 0.f, 0.f};
  f32x4 acd1 = (f32x4){0.f, 0.f, 0.f, 0.f};

  #pragma unroll 1
  for (int jc = js * 16; jc < js * 16 + 16; ++jc) {
    const int jb = jc * 32 + koff;
    const f32x4 sd0 = *(const f32x4*)(sdp + jb);
    const f32x4 sd1 = *(const f32x4*)(sdp + jb + 4);
    const i32x4 al0 = *(const i32x4*)(adjl + jb);
    const i32x4 al1 = *(const i32x4*)(adjl + jb + 4);
    const i32x4 ah0 = *(const i32x4*)(adjh + jb);
    const i32x4 ah1 = *(const i32x4*)(adjh + jb + 4);
    const short8 hb0 = *(const short8*)(ht + jc * 32);
    const short8 hb1 = *(const short8*)(ht + 16 * NN + jc * 32);
    const short8 hb2 = *(const short8*)(ht + 32 * NN + jc * 32);
    const short8 hb3 = *(const short8*)(ht + 48 * NN + jc * 32);

    float pl[8], ph[8];
    #pragma unroll
    for (int e = 0; e < 8; ++e) {
      const float sdv = (e < 4) ? sd0[e] : sd1[e - 4];
      const int   avl = (e < 4) ? al0[e] : al1[e - 4];
      const int   avh = (e < 4) ? ah0[e] : ah1[e - 4];
      float x = ssl + sdv;                 // already scaled by log2(e)
      x = fmaxf(x, 0.2f * x);
      const float p = __builtin_amdgcn_exp2f(x);
      pl[e] = avl ? p : 0.f;
      float y = ssh + sdv;
      y = fmaxf(y, 0.2f * y);
      const float q = __builtin_amdgcn_exp2f(y);
      ph[e] = avh ? q : 0.f;
    }
    u32x4 pa, pb;
    #pragma unroll
    for (int e2 = 0; e2 < 4; ++e2) {
      pa[e2] = cvtpk(pl[2 * e2], pl[2 * e2 + 1]);
      pb[e2] = cvtpk(ph[2 * e2], ph[2 * e2 + 1]);
    }
    union { u32x4 u; short8 s; } ca, cb;
    ca.u = pa; cb.u = pb;
    const short8 pal = ca.s, pah = cb.s;

    acc[0] = __builtin_amdgcn_mfma_f32_16x16x32_bf16(pal, hb0, acc[0], 0, 0, 0);
    acc[1] = __builtin_amdgcn_mfma_f32_16x16x32_bf16(pal, hb1, acc[1], 0, 0, 0);
    acc[2] = __builtin_amdgcn_mfma_f32_16x16x32_bf16(pal, hb2, acc[2], 0, 0, 0);
    acc[3] = __builtin_amdgcn_mfma_f32_16x16x32_bf16(pal, hb3, acc[3], 0, 0, 0);
    acc[4] = __builtin_amdgcn_mfma_f32_16x16x32_bf16(pah, hb0, acc[4], 0, 0, 0);
    acc[5] = __builtin_amdgcn_mfma_f32_16x16x32_bf16(pah, hb1, acc[5], 0, 0, 0);
    acc[6] = __builtin_amdgcn_mfma_f32_16x16x32_bf16(pah, hb2, acc[6], 0, 0, 0);
    acc[7] = __builtin_amdgcn_mfma_f32_16x16x32_bf16(pah, hb3, acc[7], 0, 0, 0);
    acd0   = __builtin_amdgcn_mfma_f32_16x16x32_bf16(pal, ones, acd0, 0, 0, 0);
    acd1   = __builtin_amdgcn_mfma_f32_16x16x32_bf16(pah, ones, acd1, 0, 0, 0);
  }

  // cross-js reduction into js==0 waves; [q][lane] layout = conflict-free b128
  __shared__ f32x4 red[NH][10][64];
  #pragma unroll 1
  for (int st = 1; st < 4; ++st) {
    if (js == st) {
      #pragma unroll
      for (int q = 0; q < 8; ++q) red[w][q][l] = acc[q];
      red[w][8][l] = acd0;
      red[w][9][l] = acd1;
    }
    __syncthreads();
    if (js == 0) {
      #pragma unroll
      for (int q = 0; q < 8; ++q) acc[q] += red[w][q][l];
      acd0 += red[w][8][l];
      acd1 += red[w][9][l];
    }
    __syncthreads();
  }

  if (js == 0) {
    float rl[4], rh[4];
    #pragma unroll
    for (int r = 0; r < 4; ++r) { rl[r] = 1.0f / acd0[r]; rh[r] = 1.0f / acd1[r]; }
    #pragma unroll
    for (int s = 0; s < 2; ++s) {
      #pragma unroll
      for (int t = 0; t < 4; ++t) {
        const f32x4 a = acc[s * 4 + t];
        #pragma unroll
        for (int r = 0; r < 4; ++r) {
          const int i = i0 + s * 16 + grp * 4 + r;
          const size_t oidx = ((size_t)(b * NN + i) * COLS) + w * 64 + t * 16 + r16;
          out[oidx] = a[r] * (s ? rh[r] : rl[r]);   // f32 store
        }
      }
    }
  }
}

// ---------------------------------------------------------------------------
extern "C" void kernel_launch(void* const* d_in, const int* in_sizes, int n_in,
                              void* d_out, int out_size, void* d_ws, size_t ws_size,
                              hipStream_t stream) {
  const float* nf  = (const float*)d_in[0];
  const int*   adj = (const int*)d_in[1];
  const float* W   = (const float*)d_in[2];
  const float* att = (const float*)d_in[3];

  ushort* hT    = (ushort*)d_ws;                                  // 4 MB
  float*  s_src = (float*)((char*)d_ws + (size_t)16 * 64 * NN * 2);
  float*  s_dst = s_src + 16 * NN;

  hipLaunchKernelGGL(k1_prep, dim3(512), dim3(256), 0, stream,
                     nf, W, att, hT, s_src, s_dst);
  hipLaunchKernelGGL(k2_main, dim3(256), dim3(1024), 0, stream,
                     adj, hT, s_src, s_dst, (float*)d_out);
}

// Round 6
// 56.425 us; speedup vs baseline: 1.4983x; 1.4983x over previous
//
#include <hip/hip_runtime.h>

#define NN 2048
#define NH 4
#define COLS 256   // NH*F_OUT

typedef __attribute__((ext_vector_type(8))) short short8;
typedef __attribute__((ext_vector_type(4))) float f32x4;
typedef __attribute__((ext_vector_type(4))) int i32x4;
typedef __attribute__((ext_vector_type(4))) unsigned u32x4;

__device__ __forceinline__ ushort f2bf(float x) {
  union { float f; unsigned u; } v; v.f = x;
  unsigned r = v.u + 0x7fffu + ((v.u >> 16) & 1u);
  return (ushort)(r >> 16);
}
__device__ __forceinline__ unsigned cvtpk(float lo, float hi) {
  unsigned r;
  asm("v_cvt_pk_bf16_f32 %0, %1, %2" : "=v"(r) : "v"(lo), "v"(hi));
  return r;
}
__device__ __forceinline__ unsigned pack16(i32x4 a, i32x4 b, i32x4 c, i32x4 d) {
  unsigned m = 0;
  #pragma unroll
  for (int e = 0; e < 4; ++e) {
    m |= (a[e] != 0 ? 1u : 0u) << e;
    m |= (b[e] != 0 ? 1u : 0u) << (e + 4);
    m |= (c[e] != 0 ? 1u : 0u) << (e + 8);
    m |= (d[e] != 0 ? 1u : 0u) << (e + 12);
  }
  return m;
}

// ---------------------------------------------------------------------------
// Kernel 1: h = X @ W (f32 accum), emit:
//   hB : bf16 in MFMA B-fragment-contiguous order:
//        addr/8 = ((bh*64 + jc)*4 + t)*64 + (grp*16 + fl)
//        holding h[n = jc*32+grp*8+e][f = t*16+fl], e = 0..7 within the 16B.
//        (verified equivalent to hT round-2 layout; wave reads = 1KB bursts)
//   s_src/s_dst : f32 [bh][n], PRE-SCALED by log2(e) for exp2 in k2.
// ---------------------------------------------------------------------------
__global__ __launch_bounds__(256) void k1_prep(
    const float* __restrict__ nf, const float* __restrict__ W,
    const float* __restrict__ att, ushort* __restrict__ hB,
    float* __restrict__ s_src, float* __restrict__ s_dst)
{
  const int tid = threadIdx.x;
  const int head = tid >> 6, lane = tid & 63;
  const int bid = blockIdx.x;

  float w[64];
  #pragma unroll
  for (int f = 0; f < 64; ++f) w[f] = W[f * COLS + tid];   // coalesced

  const float LOG2E = 1.4426950408889634f;
  const float asrc = att[head * 128 + lane] * LOG2E;
  const float adst = att[head * 128 + 64 + lane] * LOG2E;

  __shared__ float xs[512];
  __shared__ ushort st8[8 * 256];

  #pragma unroll 1
  for (int g = 0; g < 2; ++g) {
    const int m0 = bid * 16 + g * 8;
    __syncthreads();
    xs[tid]       = nf[m0 * 64 + tid];
    xs[tid + 256] = nf[m0 * 64 + 256 + tid];
    __syncthreads();

    #pragma unroll
    for (int rr = 0; rr < 8; ++rr) {
      float acc = 0.f;
      #pragma unroll
      for (int f = 0; f < 64; ++f) acc = fmaf(xs[rr * 64 + f], w[f], acc);
      st8[rr * 256 + tid] = f2bf(acc);
      float vs = acc * asrc, vd = acc * adst;
      #pragma unroll
      for (int off = 32; off > 0; off >>= 1) {
        vs += __shfl_xor(vs, off);
        vd += __shfl_xor(vd, off);
      }
      if (lane == 0) {
        const int m = m0 + rr;
        const int b = m >> 11, n = m & (NN - 1);
        s_src[(b * NH + head) * NN + n] = vs;
        s_dst[(b * NH + head) * NN + n] = vd;
      }
    }
    __syncthreads();
    // flush 8 rows -> fragment-contiguous hB (16B per thread, coalesced)
    {
      const int t = (tid >> 4) & 3, fl = tid & 15;
      const int col = head * 64 + t * 16 + fl;          // == tid
      unsigned pk[4];
      #pragma unroll
      for (int e = 0; e < 4; ++e) {
        const unsigned lo = st8[(2 * e) * 256 + col];
        const unsigned hi = st8[(2 * e + 1) * 256 + col];
        pk[e] = lo | (hi << 16);
      }
      const int b   = m0 >> 11;
      const int jc  = (m0 & (NN - 1)) >> 5;
      const int grp = (m0 & 31) >> 3;
      const size_t chunk =
          (((size_t)(b * NH + head) * 64 + jc) * 4 + t) * 64 + (grp * 16 + fl);
      uint4 vv; vv.x = pk[0]; vv.y = pk[1]; vv.z = pk[2]; vv.w = pk[3];
      *(uint4*)(hB + chunk * 8) = vv;
    }
  }
}

// ---------------------------------------------------------------------------
// Kernel 2: fused mask + leakyrelu + softmax + P@H via MFMA 16x16x32 bf16.
// grid 256 (XCD-swizzled) x 1024 threads; wave = (head, js-quarter).
// adj is staged ONCE, coalesced, packed to bits in LDS (4 pipelined steps of
// 4 jc-iters each, double-buffered). hB reads are 1KB wave-contiguous bursts.
// ---------------------------------------------------------------------------
__global__ __launch_bounds__(1024) void k2_main(
    const int* __restrict__ adj, const ushort* __restrict__ hB,
    const float* __restrict__ s_src, const float* __restrict__ s_dst,
    float* __restrict__ out)
{
  const int tid = threadIdx.x;
  const int wv  = tid >> 6;
  const int w   = wv >> 2;            // head
  const int js  = wv & 3;             // j-quarter
  const int l   = tid & 63;
  int bid = blockIdx.x;
  bid = (bid & 7) * 32 + (bid >> 3);  // bijective XCD swizzle (grid=256)
  const int b   = bid >> 6;
  const int i0  = (bid & 63) << 5;

  const int bh   = b * NH + w;
  const int r16  = l & 15;
  const int grp  = l >> 4;
  const int koff = grp << 3;

  // staging role: thread covers (sjs, srow, 16 cols at soct*16)
  const int sjs = tid >> 8, srow = (tid >> 3) & 31, soct = tid & 7;
  const int* sbase = adj + ((size_t)b * NN + i0 + srow) * NN + sjs * 512 + soct * 16;

  const float ssl = s_src[bh * NN + i0 + r16];
  const float ssh = s_src[bh * NN + i0 + 16 + r16];
  const float*  sdp = s_dst + bh * NN;
  const ushort* hbW = hB + (size_t)bh * 131072 + l * 8;

  __shared__ unsigned abits[2][4][32][4];   // [buf][js][row][jcL] 4KB
  __shared__ f32x4 red[NH][10][64];         // 40KB epilogue reduction

  const short8 ones = {(short)0x3F80, (short)0x3F80, (short)0x3F80, (short)0x3F80,
                       (short)0x3F80, (short)0x3F80, (short)0x3F80, (short)0x3F80};

  f32x4 acc[8];
  #pragma unroll
  for (int q = 0; q < 8; ++q) acc[q] = (f32x4){0.f, 0.f, 0.f, 0.f};
  f32x4 acd0 = (f32x4){0.f, 0.f, 0.f, 0.f};
  f32x4 acd1 = (f32x4){0.f, 0.f, 0.f, 0.f};

  // prologue: stage step 0
  {
    const i32x4 ra0 = *(const i32x4*)(sbase + 0);
    const i32x4 ra1 = *(const i32x4*)(sbase + 4);
    const i32x4 ra2 = *(const i32x4*)(sbase + 8);
    const i32x4 ra3 = *(const i32x4*)(sbase + 12);
    ushort* p = (ushort*)&abits[0][sjs][srow][0];
    p[soct] = (ushort)pack16(ra0, ra1, ra2, ra3);
  }
  __syncthreads();

  #pragma unroll 1
  for (int s = 0; s < 4; ++s) {
    // issue next step's global loads early (latency hides under compute)
    i32x4 ra0, ra1, ra2, ra3;
    if (s < 3) {
      const int* sp = sbase + (s + 1) * 128;
      ra0 = *(const i32x4*)(sp + 0);
      ra1 = *(const i32x4*)(sp + 4);
      ra2 = *(const i32x4*)(sp + 8);
      ra3 = *(const i32x4*)(sp + 12);
    }
    const int cur = s & 1;

    #pragma unroll
    for (int q4 = 0; q4 < 4; ++q4) {
      const int jc = js * 16 + s * 4 + q4;
      const unsigned wlo = abits[cur][js][r16][q4];
      const unsigned whi = abits[cur][js][r16 + 16][q4];
      const int jb = jc * 32 + koff;
      const f32x4 sd0 = *(const f32x4*)(sdp + jb);
      const f32x4 sd1 = *(const f32x4*)(sdp + jb + 4);
      const ushort* hc = hbW + jc * 2048;
      const short8 hb0 = *(const short8*)(hc);
      const short8 hb1 = *(const short8*)(hc + 512);
      const short8 hb2 = *(const short8*)(hc + 1024);
      const short8 hb3 = *(const short8*)(hc + 1536);

      float pl[8], ph[8];
      #pragma unroll
      for (int e = 0; e < 8; ++e) {
        const float sdv = (e < 4) ? sd0[e] : sd1[e - 4];
        float x = ssl + sdv;                 // scaled by log2(e) in k1
        x = fmaxf(x, 0.2f * x);
        const float p = __builtin_amdgcn_exp2f(x);
        pl[e] = ((wlo >> (koff + e)) & 1u) ? p : 0.f;
        float y = ssh + sdv;
        y = fmaxf(y, 0.2f * y);
        const float qv = __builtin_amdgcn_exp2f(y);
        ph[e] = ((whi >> (koff + e)) & 1u) ? qv : 0.f;
      }
      u32x4 pa, pb;
      #pragma unroll
      for (int e2 = 0; e2 < 4; ++e2) {
        pa[e2] = cvtpk(pl[2 * e2], pl[2 * e2 + 1]);
        pb[e2] = cvtpk(ph[2 * e2], ph[2 * e2 + 1]);
      }
      union { u32x4 u; short8 s; } ca, cb;
      ca.u = pa; cb.u = pb;
      const short8 pal = ca.s, pah = cb.s;

      acc[0] = __builtin_amdgcn_mfma_f32_16x16x32_bf16(pal, hb0, acc[0], 0, 0, 0);
      acc[1] = __builtin_amdgcn_mfma_f32_16x16x32_bf16(pal, hb1, acc[1], 0, 0, 0);
      acc[2] = __builtin_amdgcn_mfma_f32_16x16x32_bf16(pal, hb2, acc[2], 0, 0, 0);
      acc[3] = __builtin_amdgcn_mfma_f32_16x16x32_bf16(pal, hb3, acc[3], 0, 0, 0);
      acc[4] = __builtin_amdgcn_mfma_f32_16x16x32_bf16(pah, hb0, acc[4], 0, 0, 0);
      acc[5] = __builtin_amdgcn_mfma_f32_16x16x32_bf16(pah, hb1, acc[5], 0, 0, 0);
      acc[6] = __builtin_amdgcn_mfma_f32_16x16x32_bf16(pah, hb2, acc[6], 0, 0, 0);
      acc[7] = __builtin_amdgcn_mfma_f32_16x16x32_bf16(pah, hb3, acc[7], 0, 0, 0);
      acd0   = __builtin_amdgcn_mfma_f32_16x16x32_bf16(pal, ones, acd0, 0, 0, 0);
      acd1   = __builtin_amdgcn_mfma_f32_16x16x32_bf16(pah, ones, acd1, 0, 0, 0);
    }

    // pack + write next buffer, then one barrier per step
    if (s < 3) {
      ushort* p = (ushort*)&abits[cur ^ 1][sjs][srow][0];
      p[soct] = (ushort)pack16(ra0, ra1, ra2, ra3);
    }
    __syncthreads();
  }

  // cross-js reduction into js==0 waves
  #pragma unroll 1
  for (int st = 1; st < 4; ++st) {
    if (js == st) {
      #pragma unroll
      for (int q = 0; q < 8; ++q) red[w][q][l] = acc[q];
      red[w][8][l] = acd0;
      red[w][9][l] = acd1;
    }
    __syncthreads();
    if (js == 0) {
      #pragma unroll
      for (int q = 0; q < 8; ++q) acc[q] += red[w][q][l];
      acd0 += red[w][8][l];
      acd1 += red[w][9][l];
    }
    __syncthreads();
  }

  if (js == 0) {
    float rl[4], rh[4];
    #pragma unroll
    for (int r = 0; r < 4; ++r) { rl[r] = 1.0f / acd0[r]; rh[r] = 1.0f / acd1[r]; }
    #pragma unroll
    for (int sx = 0; sx < 2; ++sx) {
      #pragma unroll
      for (int t = 0; t < 4; ++t) {
        const f32x4 a = acc[sx * 4 + t];
        #pragma unroll
        for (int r = 0; r < 4; ++r) {
          const int i = i0 + sx * 16 + grp * 4 + r;
          const size_t oidx = ((size_t)(b * NN + i) * COLS) + w * 64 + t * 16 + r16;
          out[oidx] = a[r] * (sx ? rh[r] : rl[r]);
        }
      }
    }
  }
}

// ---------------------------------------------------------------------------
extern "C" void kernel_launch(void* const* d_in, const int* in_sizes, int n_in,
                              void* d_out, int out_size, void* d_ws, size_t ws_size,
                              hipStream_t stream) {
  const float* nf  = (const float*)d_in[0];
  const int*   adj = (const int*)d_in[1];
  const float* W   = (const float*)d_in[2];
  const float* att = (const float*)d_in[3];

  ushort* hB    = (ushort*)d_ws;                                  // 4 MB
  float*  s_src = (float*)((char*)d_ws + (size_t)16 * 64 * NN * 2);
  float*  s_dst = s_src + 16 * NN;

  hipLaunchKernelGGL(k1_prep, dim3(512), dim3(256), 0, stream,
                     nf, W, att, hB, s_src, s_dst);
  hipLaunchKernelGGL(k2_main, dim3(256), dim3(1024), 0, stream,
                     adj, hB, s_src, s_dst, (float*)d_out);
}